// Round 1
// baseline (2737.195 us; speedup 1.0000x reference)
//
#include <hip/hip_runtime.h>

// Neural-ODE RK4 integrator, persistent batch-parallel kernel.
// B=1024 rows split over 64 blocks x 16 rows. 8 waves/block, each wave owns
// 32 of the 256 hidden columns. Weights: layers 1..3 fp16 in VGPRs
// (192 VGPR/wave), layer 0 fp16 in LDS (128 KB, B-frag-gathered layout).
// Activations exchanged per layer through a double-buffered 8 KB LDS tile
// stored pre-gathered in MFMA A-fragment order (conflict-free ds_read_b128).
// RK4 state (y, ksum) stays fp32 in registers; only matmul operands are fp16.

#define B_ 1024
#define T_ 128
#define IN_ 32
#define H_ 256
#define OUT_ 32

typedef _Float16 half8 __attribute__((ext_vector_type(8)));
typedef float f32x4 __attribute__((ext_vector_type(4)));

__device__ __forceinline__ float lipswish_f(float x) {
    return 0.909f * x / (1.f + __expf(-x));
}

// One hidden/final layer matmul: acc[t] = A(hin) @ W(layer LY), 16x16x32 f16 MFMA.
// A-frag (lane l, ks): hin element h[l&15][ks*32 + (l>>4)*8 + j], stored gathered
// so lane l reads its own contiguous 16B at (ks*64+l)*8.
template<int LY>
__device__ __forceinline__ void do_layer(const half8 (&wreg)[3][2][8],
                                         const _Float16* __restrict__ w0_lds,
                                         const _Float16* __restrict__ hin,
                                         int w, int l, f32x4 (&acc)[2])
{
    __syncthreads();  // h buffer written by all waves must be visible
    half8 af[8];
#pragma unroll
    for (int ks = 0; ks < 8; ++ks)
        af[ks] = *(const half8*)&hin[(ks*64 + l)*8];
    acc[0] = f32x4{0.f,0.f,0.f,0.f};
    acc[1] = f32x4{0.f,0.f,0.f,0.f};
#pragma unroll
    for (int ks = 0; ks < 8; ++ks) {
#pragma unroll
        for (int t = 0; t < 2; ++t) {
            half8 bfrag;
            if constexpr (LY == 0)
                bfrag = *(const half8*)&w0_lds[((ks*16 + (w*2 + t))*64 + l)*8];
            else
                bfrag = wreg[LY-1][t][ks];
            acc[t] = __builtin_amdgcn_mfma_f32_16x16x32_f16(af[ks], bfrag, acc[t], 0, 0, 0);
        }
    }
}

__global__ __launch_bounds__(512, 2) void ncde_kernel(
    const float* __restrict__ coeffs,   // [B,T,IN]
    const float* __restrict__ times,    // [T]
    const float* __restrict__ W_init,   // [IN,H]
    const float* __restrict__ b_init,   // [H]
    const float* __restrict__ Wf,       // [L+1,H,H]
    const float* __restrict__ bfv,      // [L+1,H]
    _Float16* __restrict__ ybuf)        // [64][T][512][8] fp16 (gathered layout)
{
    extern __shared__ char smem[];
    _Float16* w0_lds  = (_Float16*)smem;                    // 65536 halfs = 128 KB
    _Float16* h_base  = (_Float16*)(smem + 131072);         // 2 x 4096 halfs = 16 KB
    float*    bias_lds = (float*)(smem + 131072 + 16384);   // 4 KB
    float*    times_lds = (float*)(smem + 131072 + 16384 + 4096); // 512 B

    const int tid = threadIdx.x;
    const int l   = tid & 63;
    const int w   = tid >> 6;
    const int bc  = blockIdx.x;

    auto hbuf = [&](int s) { return h_base + s*4096; };

    // ---- prologue: stage times, biases, layer-0 weights (gathered B-frag layout) ----
    if (tid < T_) times_lds[tid] = times[tid];
    for (int i = tid; i < 4*H_; i += 512) bias_lds[i] = bfv[i];

    for (int idx = tid; idx < 8*16*64; idx += 512) {
        int ks = idx >> 10;
        int tn = (idx >> 6) & 15;
        int ln = idx & 63;
        int col = tn*16 + (ln & 15);
        int rowbase = ks*32 + ((ln >> 4) << 3);
        _Float16* dst = &w0_lds[idx*8];
        const float* src = &Wf[(size_t)rowbase*H_ + col];   // layer 0
#pragma unroll
        for (int j = 0; j < 8; ++j) dst[j] = (_Float16)src[(size_t)j*H_];
    }

    // ---- register weights for layers 1..3 (B-frags for this wave's 32 cols) ----
    half8 wreg[3][2][8];
#pragma unroll
    for (int ly = 1; ly <= 3; ++ly)
#pragma unroll
        for (int t = 0; t < 2; ++t)
#pragma unroll
            for (int ks = 0; ks < 8; ++ks) {
                int col = w*32 + t*16 + (l & 15);
                int row = ks*32 + ((l >> 4) << 3);
                const float* src = &Wf[((size_t)ly*H_ + row)*H_ + col];
                half8 v;
#pragma unroll
                for (int j = 0; j < 8; ++j) v[j] = (_Float16)src[(size_t)j*H_];
                wreg[ly-1][t][ks] = v;
            }

    // ---- y0 = coeffs[:,0,:] @ W_init + b_init (fp32 VALU, one-time) ----
    f32x4 y[2];
#pragma unroll
    for (int t = 0; t < 2; ++t) {
        int col = w*32 + t*16 + (l & 15);
        float bb = b_init[col];
#pragma unroll
        for (int r = 0; r < 4; ++r) {
            int row = ((l >> 4) << 2) + r;
            const float* crow = &coeffs[(size_t)(bc*16 + row) * (T_*IN_)];
            float s = bb;
            for (int k = 0; k < IN_; ++k)
                s += crow[k] * W_init[(size_t)k*H_ + col];
            y[t][r] = s;
        }
    }

    // scatter fp32x8 (D-layout) -> fp16 gathered A-layout in h buffer `slot`
    auto write_h = [&](int slot, const f32x4 (&v)[2]) {
        _Float16* hb = hbuf(slot);
#pragma unroll
        for (int t = 0; t < 2; ++t) {
            int col = w*32 + t*16 + (l & 15);
            int j = col & 7;
            int hi = ((col >> 3) & 3) << 4;
#pragma unroll
            for (int r = 0; r < 4; ++r) {
                int row = ((l >> 4) << 2) + r;
                hb[(w*64 + (hi | row))*8 + j] = (_Float16)v[t][r];
            }
        }
    };

    auto act_store = [&](f32x4 (&acc)[2], int ly, int slot) {
        _Float16* hb = hbuf(slot);
#pragma unroll
        for (int t = 0; t < 2; ++t) {
            int col = w*32 + t*16 + (l & 15);
            float bb = bias_lds[ly*H_ + col];
            int j = col & 7;
            int hi = ((col >> 3) & 3) << 4;
#pragma unroll
            for (int r = 0; r < 4; ++r) {
                float x = acc[t][r] + bb;
                int row = ((l >> 4) << 2) + r;
                hb[(w*64 + (hi | row))*8 + j] = (_Float16)lipswish_f(x);
            }
        }
    };

    // f(y): 4 layers; input at hbuf(cur); leaves cur at the h3 buffer
    auto eval_f = [&](int& cur, f32x4 (&kout)[2]) {
        f32x4 acc[2];
        do_layer<0>(wreg, w0_lds, hbuf(cur), w, l, acc);
        act_store(acc, 0, cur ^ 1); cur ^= 1;
        do_layer<1>(wreg, w0_lds, hbuf(cur), w, l, acc);
        act_store(acc, 1, cur ^ 1); cur ^= 1;
        do_layer<2>(wreg, w0_lds, hbuf(cur), w, l, acc);
        act_store(acc, 2, cur ^ 1); cur ^= 1;
        do_layer<3>(wreg, w0_lds, hbuf(cur), w, l, acc);
#pragma unroll
        for (int t = 0; t < 2; ++t) {
            int col = w*32 + t*16 + (l & 15);
            float bb = bias_lds[3*H_ + col];
#pragma unroll
            for (int r = 0; r < 4; ++r) kout[t][r] = acc[t][r] + bb;
        }
    };

    // coalesced dump of current h buffer (= fp16 y) to global scratch
    auto dump_y = [&](int cur, int tstep) {
        __syncthreads();
        uint4 v = *(const uint4*)(hbuf(cur) + tid*8);
        *(uint4*)(ybuf + ((size_t)(bc*T_ + tstep)*512 + tid)*8) = v;
    };

    int cur = 0;
    write_h(cur, y);
    dump_y(cur, 0);

    for (int st = 0; st < T_-1; ++st) {
        float dt = times_lds[st+1] - times_lds[st];
        f32x4 k[2], ksum[2], yn[2];

        eval_f(cur, k);                                   // k1
#pragma unroll
        for (int t = 0; t < 2; ++t) { ksum[t] = k[t]; yn[t] = y[t] + (0.5f*dt)*k[t]; }
        write_h(cur ^ 1, yn); cur ^= 1;

        eval_f(cur, k);                                   // k2
#pragma unroll
        for (int t = 0; t < 2; ++t) { ksum[t] += 2.f*k[t]; yn[t] = y[t] + (0.5f*dt)*k[t]; }
        write_h(cur ^ 1, yn); cur ^= 1;

        eval_f(cur, k);                                   // k3
#pragma unroll
        for (int t = 0; t < 2; ++t) { ksum[t] += 2.f*k[t]; yn[t] = y[t] + dt*k[t]; }
        write_h(cur ^ 1, yn); cur ^= 1;

        eval_f(cur, k);                                   // k4
#pragma unroll
        for (int t = 0; t < 2; ++t) { ksum[t] += k[t]; y[t] = y[t] + (dt/6.f)*ksum[t]; }
        write_h(cur ^ 1, y); cur ^= 1;
        dump_y(cur, st + 1);
    }
}

// projection: z[b,t,:] = y[b,t,:] @ Wd + bd.  One wave per (16-row chunk, t).
__global__ __launch_bounds__(64) void proj_kernel(
    const _Float16* __restrict__ ybuf,
    const float* __restrict__ Wd,   // [H,OUT]
    const float* __restrict__ bd,   // [OUT]
    float* __restrict__ out)        // [B,T,OUT]
{
    const int l = threadIdx.x;
    const int blk = blockIdx.x;          // bc*T + t
    const int bc = blk >> 7;
    const int t  = blk & (T_-1);

    half8 af[8];
#pragma unroll
    for (int ks = 0; ks < 8; ++ks)
        af[ks] = *(const half8*)&ybuf[((size_t)blk*512 + ks*64 + l)*8];

    f32x4 acc[2];
    acc[0] = f32x4{0.f,0.f,0.f,0.f};
    acc[1] = f32x4{0.f,0.f,0.f,0.f};
#pragma unroll
    for (int ks = 0; ks < 8; ++ks) {
#pragma unroll
        for (int t2 = 0; t2 < 2; ++t2) {
            int col = t2*16 + (l & 15);
            int row = ks*32 + ((l >> 4) << 3);
            const float* src = &Wd[(size_t)row*OUT_ + col];
            half8 bfrag;
#pragma unroll
            for (int j = 0; j < 8; ++j) bfrag[j] = (_Float16)src[(size_t)j*OUT_];
            acc[t2] = __builtin_amdgcn_mfma_f32_16x16x32_f16(af[ks], bfrag, acc[t2], 0, 0, 0);
        }
    }
#pragma unroll
    for (int t2 = 0; t2 < 2; ++t2) {
        int col = t2*16 + (l & 15);
        float bb = bd[col];
#pragma unroll
        for (int r = 0; r < 4; ++r) {
            int row = ((l >> 4) << 2) + r;
            out[((size_t)(bc*16 + row)*T_ + t)*OUT_ + col] = acc[t2][r] + bb;
        }
    }
}

extern "C" void kernel_launch(void* const* d_in, const int* in_sizes, int n_in,
                              void* d_out, int out_size, void* d_ws, size_t ws_size,
                              hipStream_t stream) {
    const float* coeffs = (const float*)d_in[0];
    const float* times  = (const float*)d_in[1];
    const float* W_init = (const float*)d_in[2];
    const float* b_init = (const float*)d_in[3];
    const float* Wf     = (const float*)d_in[4];
    const float* bfv    = (const float*)d_in[5];
    const float* Wd     = (const float*)d_in[6];
    const float* bd     = (const float*)d_in[7];
    _Float16* ybuf = (_Float16*)d_ws;           // 64*128*512*8 halfs = 67 MB
    float* out = (float*)d_out;

    const size_t lds_bytes = 131072 + 16384 + 4096 + 512;   // 152,064 B <= 160 KiB
    hipLaunchKernelGGL(ncde_kernel, dim3(64), dim3(512), lds_bytes, stream,
                       coeffs, times, W_init, b_init, Wf, bfv, ybuf);
    hipLaunchKernelGGL(proj_kernel, dim3(64*T_), dim3(64), 0, stream,
                       ybuf, Wd, bd, out);
}

// Round 2
// 1934.485 us; speedup vs baseline: 1.4149x; 1.4149x over previous
//
#include <hip/hip_runtime.h>

// Neural-ODE RK4, swapped-operand MFMA formulation: z^T = W^T @ h^T.
// 64 blocks x 16 batch rows, 8 waves x 32 hidden cols (2 M-tiles of 16).
// A-operand = W^T fragments: layers 1..3 in VGPRs (192/wave), layer 0 in LDS
// (128 KB, frag-gathered). B-operand = h^T fragment == A-fragment of h ->
// plain [16][256] fp16 LDS tile, XOR-swizzled (byte ^= (row&7)<<4), read as
// conflict-free ds_read_b128, written as 2x ds_write_b64 per thread.
// RK4 state fp32 in registers. amdgpu_waves_per_eu(2,2) pins the 256-VGPR
// budget so the weight array cannot be demoted to scratch (round-1 bug:
// VGPR_Count=128 + 227MB spill writes).

#define T_ 128
#define IN_ 32
#define H_ 256

typedef _Float16 half8 __attribute__((ext_vector_type(8)));
typedef _Float16 half4 __attribute__((ext_vector_type(4)));
typedef float f32x4 __attribute__((ext_vector_type(4)));

__device__ __forceinline__ f32x4 mfma16(half8 a, half8 b, f32x4 c) {
    return __builtin_amdgcn_mfma_f32_16x16x32_f16(a, b, c, 0, 0, 0);
}

__device__ __forceinline__ half4 cvt4(f32x4 v) {
    half4 h;
    h[0] = (_Float16)v[0]; h[1] = (_Float16)v[1];
    h[2] = (_Float16)v[2]; h[3] = (_Float16)v[3];
    return h;
}

__device__ __forceinline__ f32x4 lips4(f32x4 v) {
    f32x4 r;
#pragma unroll
    for (int e = 0; e < 4; ++e) {
        float x = v[e];
        r[e] = 0.909f * x / (1.f + __expf(-x));
    }
    return r;
}

// h-tile read: logical (row=lr, colbyte = ks*64 + lk*16), phys = row*512 +
// (colbyte ^ ((row&7)<<4)).  Decomposed: hb2 covers bits<6, sswz bit 6.
#define RDH(BUFB, KS) (*(const half8*)(ht + (BUFB) + hb2 + (((KS)*64) ^ sswz)))
#define RDA(C, KS)    (*(const half8*)(w0b + (C)*8192 + (KS)*1024))

#define STORE_TILE(BUFB, V0, V1) do {                 \
    *(half4*)(ht + (BUFB) + wo0)        = cvt4(V0);   \
    *(half4*)(ht + (BUFB) + (wo0 ^ 32)) = cvt4(V1);   \
} while (0)

#define LAYER_REG(LYI, BUFB) do {                      \
    half8 b0 = RDH(BUFB, 0), b1 = RDH(BUFB, 1);        \
    acc0 = mfma16(wreg[LYI][0][0], b0, acc0);          \
    acc1 = mfma16(wreg[LYI][1][0], b0, acc1);          \
    b0 = RDH(BUFB, 2);                                 \
    acc0 = mfma16(wreg[LYI][0][1], b1, acc0);          \
    acc1 = mfma16(wreg[LYI][1][1], b1, acc1);          \
    b1 = RDH(BUFB, 3);                                 \
    acc0 = mfma16(wreg[LYI][0][2], b0, acc0);          \
    acc1 = mfma16(wreg[LYI][1][2], b0, acc1);          \
    b0 = RDH(BUFB, 4);                                 \
    acc0 = mfma16(wreg[LYI][0][3], b1, acc0);          \
    acc1 = mfma16(wreg[LYI][1][3], b1, acc1);          \
    b1 = RDH(BUFB, 5);                                 \
    acc0 = mfma16(wreg[LYI][0][4], b0, acc0);          \
    acc1 = mfma16(wreg[LYI][1][4], b0, acc1);          \
    b0 = RDH(BUFB, 6);                                 \
    acc0 = mfma16(wreg[LYI][0][5], b1, acc0);          \
    acc1 = mfma16(wreg[LYI][1][5], b1, acc1);          \
    b1 = RDH(BUFB, 7);                                 \
    acc0 = mfma16(wreg[LYI][0][6], b0, acc0);          \
    acc1 = mfma16(wreg[LYI][1][6], b0, acc1);          \
    acc0 = mfma16(wreg[LYI][0][7], b1, acc0);          \
    acc1 = mfma16(wreg[LYI][1][7], b1, acc1);          \
} while (0)

#define LAYER_L0(BUFB) do {                                    \
    half8 b0 = RDH(BUFB, 0), b1 = RDH(BUFB, 1);                \
    half8 x0 = RDA(0, 0), z0 = RDA(1, 0);                      \
    half8 x1 = RDA(0, 1), z1 = RDA(1, 1);                      \
    acc0 = mfma16(x0, b0, acc0); acc1 = mfma16(z0, b0, acc1);  \
    b0 = RDH(BUFB, 2); x0 = RDA(0, 2); z0 = RDA(1, 2);         \
    acc0 = mfma16(x1, b1, acc0); acc1 = mfma16(z1, b1, acc1);  \
    b1 = RDH(BUFB, 3); x1 = RDA(0, 3); z1 = RDA(1, 3);         \
    acc0 = mfma16(x0, b0, acc0); acc1 = mfma16(z0, b0, acc1);  \
    b0 = RDH(BUFB, 4); x0 = RDA(0, 4); z0 = RDA(1, 4);         \
    acc0 = mfma16(x1, b1, acc0); acc1 = mfma16(z1, b1, acc1);  \
    b1 = RDH(BUFB, 5); x1 = RDA(0, 5); z1 = RDA(1, 5);         \
    acc0 = mfma16(x0, b0, acc0); acc1 = mfma16(z0, b0, acc1);  \
    b0 = RDH(BUFB, 6); x0 = RDA(0, 6); z0 = RDA(1, 6);         \
    acc0 = mfma16(x1, b1, acc0); acc1 = mfma16(z1, b1, acc1);  \
    b1 = RDH(BUFB, 7); x1 = RDA(0, 7); z1 = RDA(1, 7);         \
    acc0 = mfma16(x0, b0, acc0); acc1 = mfma16(z0, b0, acc1);  \
    acc0 = mfma16(x1, b1, acc0); acc1 = mfma16(z1, b1, acc1);  \
} while (0)

#define ACT_STORE(LY, BUFB) do {                                          \
    f32x4 bia0 = *(const f32x4*)(bias + (LY)*H_ + w*32 + lk*4);           \
    f32x4 bia1 = *(const f32x4*)(bias + (LY)*H_ + w*32 + 16 + lk*4);      \
    f32x4 v0 = lips4(acc0 + bia0);                                        \
    f32x4 v1 = lips4(acc1 + bia1);                                        \
    STORE_TILE(BUFB, v0, v1);                                             \
    __syncthreads();                                                      \
} while (0)

__global__ __launch_bounds__(512)
__attribute__((amdgpu_waves_per_eu(2, 2)))
void ncde_kernel(const float* __restrict__ coeffs,
                 const float* __restrict__ times,
                 const float* __restrict__ W_init,
                 const float* __restrict__ b_init,
                 const float* __restrict__ Wf,
                 const float* __restrict__ bfv,
                 _Float16* __restrict__ ybuf)
{
    extern __shared__ char smem[];
    _Float16* w0   = (_Float16*)smem;                   // 128 KiB [mt16][ks8][l64][8]
    char*     ht   = smem + 131072;                     // 2 x 8 KiB swizzled [16][256] f16
    float*    bias = (float*)(smem + 131072 + 16384);   // [4][256] f32

    const int tid = threadIdx.x;
    const int l   = tid & 63;
    const int w   = tid >> 6;
    const int lr  = l & 15;       // batch row within block's 16
    const int lk  = l >> 4;       // 0..3
    const int bc  = blockIdx.x;
    const int swz = (lr & 7) << 4;

    const int hb2  = lr*512 + ((lk*16) ^ (swz & 48));
    const int sswz = swz & 64;
    const int wo0  = lr*512 + (((w*64) | (lk*8)) ^ swz);
    const char* w0b = (const char*)w0 + (size_t)(2*w)*8192 + l*16;

    // ---------------- prologue ----------------
    for (int i = tid; i < 4*H_; i += 512) bias[i] = bfv[i];

    // layer-0 W^T A-frags into LDS: entry e=((mt*8+ks)*64+ln) holds 16B,
    // lane ln elems j: Wf[0][ks*32+(ln>>4)*8+j][mt*16+(ln&15)]
    for (int e = tid; e < 8192; e += 512) {
        int mt = e >> 9, ks = (e >> 6) & 7, ln = e & 63;
        int colh = mt*16 + (ln & 15);
        int row0 = ks*32 + ((ln >> 4) << 3);
        const float* src = Wf + (size_t)row0 * H_ + colh;
        half8 v;
#pragma unroll
        for (int j = 0; j < 8; ++j) v[j] = (_Float16)src[(size_t)j * H_];
        *(half8*)(w0 + (size_t)e * 8) = v;
    }

    // layers 1..3 W^T A-frags in VGPRs (this wave's 32 hidden cols)
    half8 wreg[3][2][8];
#pragma unroll
    for (int ly = 0; ly < 3; ++ly)
#pragma unroll
        for (int c = 0; c < 2; ++c)
#pragma unroll
            for (int ks = 0; ks < 8; ++ks) {
                const float* src = Wf + ((size_t)(ly + 1) * H_ + ks*32 + lk*8) * H_
                                      + w*32 + c*16 + lr;
                half8 v;
#pragma unroll
                for (int j = 0; j < 8; ++j) v[j] = (_Float16)src[(size_t)j * H_];
                wreg[ly][c][ks] = v;
            }

    // y0 = coeffs[:,0,:] @ W_init + b_init  (fp32 VALU, one-time)
    // lane holds y[batch=lr][hidden = w*32 + c*16 + lk*4 + r]
    f32x4 y0v, y1v;
    {
        const float* crow = coeffs + (size_t)(bc*16 + lr) * (T_ * IN_);
#pragma unroll
        for (int c = 0; c < 2; ++c) {
            f32x4 acc;
#pragma unroll
            for (int r = 0; r < 4; ++r) {
                int hcol = w*32 + c*16 + lk*4 + r;
                float s = b_init[hcol];
                for (int k = 0; k < IN_; ++k)
                    s += crow[k] * W_init[(size_t)k * H_ + hcol];
                acc[r] = s;
            }
            if (c == 0) y0v = acc; else y1v = acc;
        }
    }

    STORE_TILE(0, y0v, y1v);
    __syncthreads();
    {
        int drow = tid >> 5, dcb = (tid & 31) << 4;
        uint4 vv = *(const uint4*)(ht + drow*512 + (dcb ^ ((drow & 7) << 4)));
        *(uint4*)((char*)ybuf + ((size_t)(bc*T_) << 13) + tid*16) = vv;
    }

#pragma unroll 1
    for (int st = 0; st < T_ - 1; ++st) {
        float dt = times[st + 1] - times[st];
        f32x4 ks0, ks1;
#pragma unroll 1
        for (int s = 0; s < 4; ++s) {
            f32x4 acc0 = f32x4{0.f,0.f,0.f,0.f}, acc1 = f32x4{0.f,0.f,0.f,0.f};
            LAYER_L0(0);                    // in t0 -> out t1
            ACT_STORE(0, 8192);
            acc0 = f32x4{0.f,0.f,0.f,0.f};  acc1 = f32x4{0.f,0.f,0.f,0.f};
            LAYER_REG(0, 8192);             // layer 1: in t1 -> out t0
            ACT_STORE(1, 0);
            acc0 = f32x4{0.f,0.f,0.f,0.f};  acc1 = f32x4{0.f,0.f,0.f,0.f};
            LAYER_REG(1, 0);                // layer 2: in t0 -> out t1
            ACT_STORE(2, 8192);
            acc0 = f32x4{0.f,0.f,0.f,0.f};  acc1 = f32x4{0.f,0.f,0.f,0.f};
            LAYER_REG(2, 8192);             // layer 3: in t1 -> k (regs)
            f32x4 k0, k1;
            {
                f32x4 bia0 = *(const f32x4*)(bias + 3*H_ + w*32 + lk*4);
                f32x4 bia1 = *(const f32x4*)(bias + 3*H_ + w*32 + 16 + lk*4);
                k0 = acc0 + bia0; k1 = acc1 + bia1;
            }
            if (s == 0)     { ks0 = k0;       ks1 = k1; }
            else if (s < 3) { ks0 += 2.f*k0;  ks1 += 2.f*k1; }
            else            { ks0 += k0;      ks1 += k1; }
            if (s < 3) {
                float cy = (s == 2) ? dt : 0.5f*dt;
                f32x4 yn0 = y0v + cy*k0, yn1 = y1v + cy*k1;
                STORE_TILE(0, yn0, yn1);
            } else {
                float c6 = dt * (1.f/6.f);
                y0v += c6*ks0; y1v += c6*ks1;
                STORE_TILE(0, y0v, y1v);
            }
            __syncthreads();
        }
        {
            int drow = tid >> 5, dcb = (tid & 31) << 4;
            uint4 vv = *(const uint4*)(ht + drow*512 + (dcb ^ ((drow & 7) << 4)));
            *(uint4*)((char*)ybuf + ((size_t)(bc*T_ + st + 1) << 13) + tid*16) = vv;
        }
    }
}

// out^T = Wd^T @ y^T per (16-batch, t) tile.  One wave per (bc, 16 t-steps).
__global__ __launch_bounds__(64)
void proj_kernel(const _Float16* __restrict__ ybuf,
                 const float* __restrict__ Wd,   // [H,32]
                 const float* __restrict__ bd,   // [32]
                 float* __restrict__ out)        // [B,T,32]
{
    const int l  = threadIdx.x;
    const int lr = l & 15, lk = l >> 4;
    const int bc = blockIdx.x;
    const int tg = blockIdx.y;

    half8 wd[2][8];
#pragma unroll
    for (int c = 0; c < 2; ++c)
#pragma unroll
        for (int ks = 0; ks < 8; ++ks) {
            const float* src = Wd + (size_t)(ks*32 + lk*8) * 32 + c*16 + lr;
            half8 v;
#pragma unroll
            for (int j = 0; j < 8; ++j) v[j] = (_Float16)src[(size_t)j * 32];
            wd[c][ks] = v;
        }
    f32x4 bd0 = *(const f32x4*)(bd + lk*4);
    f32x4 bd1 = *(const f32x4*)(bd + 16 + lk*4);

    for (int t = tg*16; t < tg*16 + 16; ++t) {
        const _Float16* yt = ybuf + ((size_t)(bc*T_) + t) * 4096;
        f32x4 a0 = f32x4{0.f,0.f,0.f,0.f}, a1 = f32x4{0.f,0.f,0.f,0.f};
#pragma unroll
        for (int ks = 0; ks < 8; ++ks) {
            half8 b = *(const half8*)(yt + lr*256 + ks*32 + lk*8);
            a0 = mfma16(wd[0][ks], b, a0);
            a1 = mfma16(wd[1][ks], b, a1);
        }
        float* op = out + ((size_t)(bc*16 + lr) * T_ + t) * 32;
        *(f32x4*)(op + lk*4)      = a0 + bd0;
        *(f32x4*)(op + 16 + lk*4) = a1 + bd1;
    }
}

extern "C" void kernel_launch(void* const* d_in, const int* in_sizes, int n_in,
                              void* d_out, int out_size, void* d_ws, size_t ws_size,
                              hipStream_t stream) {
    const float* coeffs = (const float*)d_in[0];
    const float* times  = (const float*)d_in[1];
    const float* W_init = (const float*)d_in[2];
    const float* b_init = (const float*)d_in[3];
    const float* Wf     = (const float*)d_in[4];
    const float* bfv    = (const float*)d_in[5];
    const float* Wd     = (const float*)d_in[6];
    const float* bd     = (const float*)d_in[7];
    _Float16* ybuf = (_Float16*)d_ws;               // 64*128*4096 halfs = 64 MiB
    float* out = (float*)d_out;

    const size_t lds_bytes = 131072 + 16384 + 4096;  // 151,552 B <= 160 KiB
    hipLaunchKernelGGL(ncde_kernel, dim3(64), dim3(512), lds_bytes, stream,
                       coeffs, times, W_init, b_init, Wf, bfv, ybuf);
    hipLaunchKernelGGL(proj_kernel, dim3(64, 8), dim3(64), 0, stream,
                       ybuf, Wd, bd, out);
}